// Round 1
// baseline (512.861 us; speedup 1.0000x reference)
//
#include <hip/hip_runtime.h>
#include <cfloat>

#define S_CODES 1024
#define C_DIM   256
#define N_TOK   32768
#define TPB     32      // tokens per block
#define KCH     8       // k-rows per LDS chunk
#define NCHUNK  (C_DIM / KCH)

// ws layout (4-byte units):
//  [0..1023]     int   histogram
//  [1024]        float loss accumulator
//  [1056..2079]  float w2 (per-code squared norm)

__global__ void w2_kernel(const float* __restrict__ w, float* __restrict__ w2) {
    int code = blockIdx.x * blockDim.x + threadIdx.x;
    const float4* r = (const float4*)(w + (size_t)code * C_DIM);
    float s = 0.f;
#pragma unroll 8
    for (int i = 0; i < C_DIM / 4; ++i) {
        float4 v = r[i];
        s += v.x * v.x + v.y * v.y + v.z * v.z + v.w * v.w;
    }
    w2[code] = s;
}

// score[token][code] = w2[code] - 2 * dot(x[token], w[code])   (x^2 term dropped: argmin-invariant)
// per lane: 8 tokens (broadcast x) x 16 codes (4 float4 groups strided 256 codes apart)
__launch_bounds__(256, 2)
__global__ void vq_main(const float* __restrict__ x, const float* __restrict__ emb,
                        float* __restrict__ out, int* __restrict__ hist,
                        float* __restrict__ lossp, const float* __restrict__ w2) {
    __shared__ float w_lds[KCH * S_CODES];   // 32 KB, [k][code]
    __shared__ float x_lds[C_DIM * TPB];     // 32 KB, [c][t]

    const int tid = threadIdx.x;
    const int l   = tid & 63;   // lane
    const int wv  = tid >> 6;   // wave 0..3
    const int t0  = blockIdx.x * TPB;       // first token of block (never straddles a batch)
    const int b   = t0 >> 10;
    const int hw0 = t0 & 1023;
    const float* xbase = x + ((size_t)b * C_DIM << 10) + hw0;

    // ---- stage x tile: x_lds[c][t], coalesced 128B segments per channel row ----
    {
        int rl = tid & 7, r0 = tid >> 3;    // 8 lanes/row, 32 rows/rep
        for (int rep = 0; rep < 8; ++rep) {
            int c = rep * 32 + r0;
            float4 v = *(const float4*)(xbase + ((size_t)c << 10) + rl * 4);
            *(float4*)&x_lds[c * TPB + rl * 4] = v;
        }
    }

    // ---- prefetch w chunk 0 into registers ----
    float4 pre[8];
#pragma unroll
    for (int m = 0; m < 8; ++m) {
        int fid = m * 256 + tid;            // 2048 float4 per chunk
        int code = fid >> 1, kq = fid & 1;
        pre[m] = *(const float4*)(emb + (size_t)code * C_DIM + kq * 4);
    }

    float acc[8][16];
#pragma unroll
    for (int t = 0; t < 8; ++t)
#pragma unroll
        for (int j = 0; j < 16; ++j) acc[t][j] = 0.f;

    __syncthreads();    // x staged; w_lds free

    for (int chunk = 0; chunk < NCHUNK; ++chunk) {
        // write prefetched chunk to LDS (transpose k-major); 2-way bank alias only (free)
#pragma unroll
        for (int m = 0; m < 8; ++m) {
            int fid = m * 256 + tid;
            int code = fid >> 1, kq = fid & 1;
            float4 v = pre[m];
            w_lds[(kq * 4 + 0) * S_CODES + code] = v.x;
            w_lds[(kq * 4 + 1) * S_CODES + code] = v.y;
            w_lds[(kq * 4 + 2) * S_CODES + code] = v.z;
            w_lds[(kq * 4 + 3) * S_CODES + code] = v.w;
        }
        // prefetch next chunk (overlaps compute below)
        if (chunk + 1 < NCHUNK) {
            int k0n = (chunk + 1) * KCH;
#pragma unroll
            for (int m = 0; m < 8; ++m) {
                int fid = m * 256 + tid;
                int code = fid >> 1, kq = fid & 1;
                pre[m] = *(const float4*)(emb + (size_t)code * C_DIM + k0n + kq * 4);
            }
        }
        __syncthreads();

        int k0 = chunk * KCH;
#pragma unroll
        for (int kk = 0; kk < KCH; ++kk) {
            int k = k0 + kk;
            // 16 code-weights: 4x ds_read_b128, lane-stride 16B => conflict-free
            float4 wq0 = *(const float4*)&w_lds[kk * S_CODES +   0 + l * 4];
            float4 wq1 = *(const float4*)&w_lds[kk * S_CODES + 256 + l * 4];
            float4 wq2 = *(const float4*)&w_lds[kk * S_CODES + 512 + l * 4];
            float4 wq3 = *(const float4*)&w_lds[kk * S_CODES + 768 + l * 4];
            // 8 token x-values: same-address broadcast reads (cheap)
            float4 xa = *(const float4*)&x_lds[k * TPB + wv * 8];
            float4 xb = *(const float4*)&x_lds[k * TPB + wv * 8 + 4];
            float xs[8] = {xa.x, xa.y, xa.z, xa.w, xb.x, xb.y, xb.z, xb.w};
            float wvv[16] = {wq0.x, wq0.y, wq0.z, wq0.w, wq1.x, wq1.y, wq1.z, wq1.w,
                             wq2.x, wq2.y, wq2.z, wq2.w, wq3.x, wq3.y, wq3.z, wq3.w};
#pragma unroll
            for (int t = 0; t < 8; ++t) {
                float xv = xs[t];
#pragma unroll
                for (int j = 0; j < 16; ++j) acc[t][j] = fmaf(xv, wvv[j], acc[t][j]);
            }
        }
        __syncthreads();    // safe to overwrite w_lds next iter
    }

    // ---- scores + argmin ----
    float w2v[16];
#pragma unroll
    for (int m = 0; m < 4; ++m) {
        float4 v = *(const float4*)&w2[m * 256 + l * 4];
        w2v[m * 4 + 0] = v.x; w2v[m * 4 + 1] = v.y;
        w2v[m * 4 + 2] = v.z; w2v[m * 4 + 3] = v.w;
    }
    int*   idx_sh = (int*)w_lds;          // reuse (post-barrier)
    float* red    = (float*)(w_lds + 64);

#pragma unroll
    for (int t = 0; t < 8; ++t) {
        float bv = FLT_MAX; int bi = 0;
#pragma unroll
        for (int m = 0; m < 4; ++m)
#pragma unroll
            for (int j = 0; j < 4; ++j) {
                float s = w2v[m * 4 + j] - 2.f * acc[t][m * 4 + j];
                int c = m * 256 + l * 4 + j;     // ascending within lane
                if (s < bv) { bv = s; bi = c; }
            }
        // 64-lane butterfly argmin, low-index tie-break
#pragma unroll
        for (int off = 32; off > 0; off >>= 1) {
            float ov = __shfl_xor(bv, off);
            int   oi = __shfl_xor(bi, off);
            if (ov < bv || (ov == bv && oi < bi)) { bv = ov; bi = oi; }
        }
        if (l == 0) idx_sh[wv * 8 + t] = bi;
    }
    __syncthreads();

    if (tid < TPB) atomicAdd(&hist[idx_sh[tid]], 1);

    // ---- gather + output write (coalesced along tokens) + loss partial ----
    float lsum = 0.f;
    for (int e = tid; e < C_DIM * TPB; e += 256) {
        int t = e & (TPB - 1), c = e >> 5;
        int id = idx_sh[t];
        float q  = emb[(size_t)id * C_DIM + c];
        float xv = x_lds[c * TPB + t];
        float d  = q - xv;
        lsum += d * d;
        out[((size_t)(b * C_DIM + c) << 10) + hw0 + t] = q;
    }
#pragma unroll
    for (int off = 32; off > 0; off >>= 1) lsum += __shfl_down(lsum, off);
    if (l == 0) red[wv] = lsum;
    __syncthreads();
    if (tid == 0) atomicAdd(lossp, red[0] + red[1] + red[2] + red[3]);
}

__global__ void finalize_kernel(const int* __restrict__ hist, const float* __restrict__ lossp,
                                float* __restrict__ out) {
    __shared__ float red[16];
    int tid = threadIdx.x;                  // 1024 threads
    float p = (float)hist[tid] * (1.f / 32768.f);
    float term = p * logf(p + 1e-6f);
#pragma unroll
    for (int off = 32; off > 0; off >>= 1) term += __shfl_down(term, off);
    if ((tid & 63) == 0) red[tid >> 6] = term;
    __syncthreads();
    if (tid == 0) {
        float s = 0.f;
#pragma unroll
        for (int i = 0; i < 16; ++i) s += red[i];
        out[8388608] = 0.25f * lossp[0] * (1.f / 8388608.f);   // quant_loss
        out[8388609] = expf(-s);                               // perplexity
    }
}

extern "C" void kernel_launch(void* const* d_in, const int* in_sizes, int n_in,
                              void* d_out, int out_size, void* d_ws, size_t ws_size,
                              hipStream_t stream) {
    const float* x   = (const float*)d_in[0];
    const float* emb = (const float*)d_in[1];
    float* out   = (float*)d_out;
    int*   hist  = (int*)d_ws;
    float* wsf   = (float*)d_ws;
    float* lossp = wsf + 1024;
    float* w2    = wsf + 1056;

    hipMemsetAsync(d_ws, 0, 1056 * 4, stream);                 // hist + loss accum
    w2_kernel<<<4, 256, 0, stream>>>(emb, w2);
    vq_main<<<N_TOK / TPB, 256, 0, stream>>>(x, emb, out, hist, lossp, w2);
    finalize_kernel<<<1, 1024, 0, stream>>>(hist, lossp, out);
}

// Round 2
// 179.652 us; speedup vs baseline: 2.8547x; 2.8547x over previous
//
#include <hip/hip_runtime.h>
#include <hip/hip_bf16.h>
#include <cfloat>
#include <math.h>

#define N_TOK   32768
#define S_CODES 1024
#define C_DIM   256

typedef __attribute__((ext_vector_type(8))) short short8v;
typedef __attribute__((ext_vector_type(4))) float float4v;

// ---- workspace byte offsets ----
#define WS_HIST   0               // 1024 int
#define WS_LOSS   4096            // 1 float
#define WS_W2     4608            // 1024 float
#define WS_XHI    16384           // 32768*256 bf16 = 16 MB
#define WS_XLO    (WS_XHI + 16777216)
#define WS_WHI    (WS_XLO + 16777216)   // 1024*256 bf16 = 512 KB
#define WS_WLO    (WS_WHI + 524288)
#define WS_PVAL   (WS_WLO + 524288)     // 2*32768 float
#define WS_PIDX   (WS_PVAL + 262144)    // 2*32768 int
#define WS_NEED   ((size_t)(WS_PIDX + 262144))

__device__ __forceinline__ unsigned short f2bf(float f) {
    __hip_bfloat16 h = __float2bfloat16(f);
    return __builtin_bit_cast(unsigned short, h);
}
__device__ __forceinline__ float bf2f(unsigned short u) {
    return __bfloat162float(__builtin_bit_cast(__hip_bfloat16, u));
}
__device__ __forceinline__ void gload16(const void* g, void* l) {
    __builtin_amdgcn_global_load_lds((const __attribute__((address_space(1))) void*)g,
                                     (__attribute__((address_space(3))) void*)l, 16, 0, 0);
}

// ---- split w into bf16 hi/lo + squared norms ----
__global__ void split_w(const float* __restrict__ w, unsigned short* __restrict__ whi,
                        unsigned short* __restrict__ wlo, float* __restrict__ w2) {
    int c = blockIdx.x, l = threadIdx.x;       // 1024 blocks x 64 threads
    float4 v = ((const float4*)(w + (size_t)c * C_DIM))[l];
    float s = v.x*v.x + v.y*v.y + v.z*v.z + v.w*v.w;
    float vv[4] = {v.x, v.y, v.z, v.w};
    ushort4 h, lo;
    unsigned short* hp = (unsigned short*)&h;
    unsigned short* lp = (unsigned short*)&lo;
#pragma unroll
    for (int q = 0; q < 4; ++q) {
        hp[q] = f2bf(vv[q]);
        lp[q] = f2bf(vv[q] - bf2f(hp[q]));
    }
    *(ushort4*)&whi[(size_t)c * C_DIM + l*4] = h;
    *(ushort4*)&wlo[(size_t)c * C_DIM + l*4] = lo;
#pragma unroll
    for (int off = 32; off > 0; off >>= 1) s += __shfl_down(s, off);
    if (l == 0) w2[c] = s;
}

// ---- split + transpose x: [b][c][hw] f32 -> token-major [t][c] bf16 hi/lo ----
__global__ void split_x(const float* __restrict__ x, unsigned short* __restrict__ xhi,
                        unsigned short* __restrict__ xlo) {
    __shared__ float tile[64 * 65];
    int bid = blockIdx.x;
    int ht = bid & 15, ct = (bid >> 4) & 3, b = bid >> 6;   // 32 x 4 x 16
    int c0 = ct * 64, hw0 = ht * 64;
    int tid = threadIdx.x;
    int colv = tid & 63, rowq = tid >> 6;
    for (int rep = 0; rep < 16; ++rep) {
        int r = rep * 4 + rowq;                              // feature row
        tile[r * 65 + colv] = x[(((size_t)b * 256 + c0 + r) << 10) + hw0 + colv];
    }
    __syncthreads();
    int cp = tid & 31, hwq = tid >> 5;                       // pack 2 features / thread
    for (int rep = 0; rep < 8; ++rep) {
        int hw = rep * 8 + hwq;
        float v0 = tile[(2*cp)   * 65 + hw];
        float v1 = tile[(2*cp+1) * 65 + hw];
        unsigned short h0 = f2bf(v0), h1 = f2bf(v1);
        unsigned short l0 = f2bf(v0 - bf2f(h0)), l1 = f2bf(v1 - bf2f(h1));
        size_t o = ((size_t)b * 1024 + hw0 + hw) * 256 + c0 + 2*cp;
        *(unsigned int*)&xhi[o] = (unsigned int)h0 | ((unsigned int)h1 << 16);
        *(unsigned int*)&xlo[o] = (unsigned int)l0 | ((unsigned int)l1 << 16);
    }
}

// ---- main: split-bf16 MFMA GEMM + per-strip running argmin ----
// grid 512: tb = bid>>1 (128 tokens), sgrp = bid&1 (512-code group, 4 strips of 128)
__global__ void __launch_bounds__(256) __attribute__((amdgpu_waves_per_eu(2, 2)))
vq_mfma(const unsigned short* __restrict__ xhi, const unsigned short* __restrict__ xlo,
        const unsigned short* __restrict__ whi, const unsigned short* __restrict__ wlo,
        const float* __restrict__ w2g, float* __restrict__ pval, int* __restrict__ pidx) {
    // smem: xh[128][64] | xl | wh | wl  (bf16, 16 KB each, XOR-swizzled 16B chunks)
    __shared__ __align__(16) unsigned short smem[32768];
    char* smemc = (char*)smem;

    const int tid = threadIdx.x;
    const int l = tid & 63, wv = tid >> 6;
    const int wm = wv & 1, wn = wv >> 1;
    const int quad = l >> 4, lr = l & 15;
    const int tb = blockIdx.x >> 1, sgrp = blockIdx.x & 1;
    const int t0 = tb * 128;
    const int cg0 = sgrp * 512;

    // fragment byte offsets (swizzle: chunk' = chunk ^ (row&7))
    int aoff[2][4], boff[2][4];
#pragma unroll
    for (int ks = 0; ks < 2; ++ks)
#pragma unroll
        for (int i = 0; i < 4; ++i) {
            int arow = wm*64 + i*16 + lr;
            aoff[ks][i] = (arow*64 + ((ks*4 + quad) ^ (arow & 7)) * 8) * 2;
            int brow = wn*64 + i*16 + lr;
            boff[ks][i] = 32768 + (brow*64 + ((ks*4 + quad) ^ (brow & 7)) * 8) * 2;
        }

    const int srow = l >> 3;                 // staging: row within 8-row group
    const int schunk = (l & 7) ^ srow;       // global chunk to fetch (un-swizzle)
    const char* xhic = (const char*)xhi;
    const char* xloc = (const char*)xlo;
    const char* whic = (const char*)whi;
    const char* wloc = (const char*)wlo;

    float bval[16]; int bidx[16];
#pragma unroll
    for (int s = 0; s < 16; ++s) { bval[s] = FLT_MAX; bidx[s] = 0; }

    const float4v zacc = {0.f, 0.f, 0.f, 0.f};

    for (int sloc = 0; sloc < 4; ++sloc) {
        const int c0 = cg0 + sloc * 128;
        float4v acc[4][4];
#pragma unroll
        for (int i = 0; i < 4; ++i)
#pragma unroll
            for (int j = 0; j < 4; ++j) acc[i][j] = zacc;

        for (int kc = 0; kc < 4; ++kc) {
            __syncthreads();                 // previous kchunk's reads complete
#pragma unroll
            for (int m = 0; m < 4; ++m) {
                int r0 = wv * 32 + m * 8;
                int rl = r0 + srow;
                size_t goffx = ((size_t)(t0 + rl)) * 512 + kc * 128 + schunk * 16;
                size_t goffw = ((size_t)(c0 + rl)) * 512 + kc * 128 + schunk * 16;
                int lbase = r0 * 128;
                gload16(xhic + goffx, smemc + lbase);
                gload16(xloc + goffx, smemc + 16384 + lbase);
                gload16(whic + goffw, smemc + 32768 + lbase);
                gload16(wloc + goffw, smemc + 49152 + lbase);
            }
            __syncthreads();                 // staging visible

#pragma unroll
            for (int ks = 0; ks < 2; ++ks) {
                short8v ah[4], al[4], bh[4], bl[4];
#pragma unroll
                for (int i = 0; i < 4; ++i) {
                    ah[i] = *(const short8v*)(smemc + aoff[ks][i]);
                    al[i] = *(const short8v*)(smemc + aoff[ks][i] + 16384);
                    bh[i] = *(const short8v*)(smemc + boff[ks][i]);
                    bl[i] = *(const short8v*)(smemc + boff[ks][i] + 16384);
                }
#pragma unroll
                for (int i = 0; i < 4; ++i)
#pragma unroll
                    for (int j = 0; j < 4; ++j) {
                        acc[i][j] = __builtin_amdgcn_mfma_f32_16x16x32_bf16(ah[i], bh[j], acc[i][j], 0, 0, 0);
                        acc[i][j] = __builtin_amdgcn_mfma_f32_16x16x32_bf16(ah[i], bl[j], acc[i][j], 0, 0, 0);
                        acc[i][j] = __builtin_amdgcn_mfma_f32_16x16x32_bf16(al[i], bh[j], acc[i][j], 0, 0, 0);
                    }
            }
        }

        // fold this 128-code strip into running per-token argmin
#pragma unroll
        for (int j = 0; j < 4; ++j) {
            int code = c0 + wn * 64 + j * 16 + lr;
            float w2c = w2g[code];
#pragma unroll
            for (int i = 0; i < 4; ++i)
#pragma unroll
                for (int rr = 0; rr < 4; ++rr) {
                    float sv = fmaf(-2.f, acc[i][j][rr], w2c);
                    int slot = i * 4 + rr;
                    if (sv < bval[slot]) { bval[slot] = sv; bidx[slot] = code; }
                }
        }
    }

    // reduce across the 16 lanes sharing each token (code dimension)
    __syncthreads();                         // done with smem as tiles; alias for merge
    float* btv = (float*)smemc;              // [2][128]
    int*   bti = (int*)(smemc + 1024);       // [2][128]
#pragma unroll
    for (int slot = 0; slot < 16; ++slot) {
        float bv = bval[slot]; int bi = bidx[slot];
#pragma unroll
        for (int off = 1; off < 16; off <<= 1) {
            float ov = __shfl_xor(bv, off);
            int   oi = __shfl_xor(bi, off);
            if (ov < bv || (ov == bv && oi < bi)) { bv = ov; bi = oi; }
        }
        if (lr == 0) {
            int tl = wm * 64 + (slot >> 2) * 16 + quad * 4 + (slot & 3);
            btv[wn * 128 + tl] = bv; bti[wn * 128 + tl] = bi;
        }
    }
    __syncthreads();
    if (tid < 128) {
        float v0 = btv[tid], v1 = btv[128 + tid];
        int   i0 = bti[tid], i1 = bti[128 + tid];
        bool take1 = (v1 < v0) || (v1 == v0 && i1 < i0);
        pval[sgrp * N_TOK + t0 + tid] = take1 ? v1 : v0;
        pidx[sgrp * N_TOK + t0 + tid] = take1 ? i1 : i0;
    }
}

// ---- merge partials, histogram, gather, output write, loss ----
__global__ void emit(const float* __restrict__ x, const float* __restrict__ emb,
                     const float* __restrict__ pval, const int* __restrict__ pidx,
                     float* __restrict__ out, int* __restrict__ hist, float* __restrict__ lossp) {
    __shared__ int idx_sh[128];
    __shared__ float red[4];
    int tid = threadIdx.x;
    int t0 = blockIdx.x * 128;
    if (tid < 128) {
        int t = t0 + tid;
        float v0 = pval[t], v1 = pval[N_TOK + t];
        int   i0 = pidx[t], i1 = pidx[N_TOK + t];
        bool take1 = (v1 < v0) || (v1 == v0 && i1 < i0);
        int id = take1 ? i1 : i0;
        idx_sh[tid] = id;
        atomicAdd(&hist[id], 1);
    }
    __syncthreads();
    int tl = tid & 127, half = tid >> 7;
    int id = idx_sh[tl];
    int bb = t0 >> 10, hw0 = t0 & 1023;
    const float* erow = emb + (size_t)id * C_DIM;
    float lsum = 0.f;
    for (int it = 0; it < 128; ++it) {
        int c = it * 2 + half;
        float q = erow[c];
        size_t go = (((size_t)bb * 256 + c) << 10) + hw0 + tl;
        float xv = x[go];
        out[go] = q;
        float d = q - xv;
        lsum = fmaf(d, d, lsum);
    }
#pragma unroll
    for (int off = 32; off > 0; off >>= 1) lsum += __shfl_down(lsum, off);
    if ((tid & 63) == 0) red[tid >> 6] = lsum;
    __syncthreads();
    if (tid == 0) atomicAdd(lossp, red[0] + red[1] + red[2] + red[3]);
}

// ---- fallback path (round-1 kernel, known-correct) ----
__global__ void w2_kernel(const float* __restrict__ w, float* __restrict__ w2) {
    int code = blockIdx.x * blockDim.x + threadIdx.x;
    const float4* r = (const float4*)(w + (size_t)code * C_DIM);
    float s = 0.f;
#pragma unroll 8
    for (int i = 0; i < C_DIM / 4; ++i) {
        float4 v = r[i];
        s += v.x * v.x + v.y * v.y + v.z * v.z + v.w * v.w;
    }
    w2[code] = s;
}

__launch_bounds__(256, 2)
__global__ void vq_main(const float* __restrict__ x, const float* __restrict__ emb,
                        float* __restrict__ out, int* __restrict__ hist,
                        float* __restrict__ lossp, const float* __restrict__ w2) {
    __shared__ float w_lds[8 * S_CODES];
    __shared__ float x_lds[C_DIM * 32];
    const int tid = threadIdx.x;
    const int l = tid & 63, wv = tid >> 6;
    const int t0 = blockIdx.x * 32;
    const int b = t0 >> 10, hw0 = t0 & 1023;
    const float* xbase = x + ((size_t)b * C_DIM << 10) + hw0;
    {
        int rl = tid & 7, r0 = tid >> 3;
        for (int rep = 0; rep < 8; ++rep) {
            int c = rep * 32 + r0;
            float4 v = *(const float4*)(xbase + ((size_t)c << 10) + rl * 4);
            *(float4*)&x_lds[c * 32 + rl * 4] = v;
        }
    }
    float4 pre[8];
#pragma unroll
    for (int m = 0; m < 8; ++m) {
        int fid = m * 256 + tid;
        int code = fid >> 1, kq = fid & 1;
        pre[m] = *(const float4*)(emb + (size_t)code * C_DIM + kq * 4);
    }
    float acc[8][16];
#pragma unroll
    for (int t = 0; t < 8; ++t)
#pragma unroll
        for (int j = 0; j < 16; ++j) acc[t][j] = 0.f;
    __syncthreads();
    for (int chunk = 0; chunk < 32; ++chunk) {
#pragma unroll
        for (int m = 0; m < 8; ++m) {
            int fid = m * 256 + tid;
            int code = fid >> 1, kq = fid & 1;
            float4 v = pre[m];
            w_lds[(kq * 4 + 0) * S_CODES + code] = v.x;
            w_lds[(kq * 4 + 1) * S_CODES + code] = v.y;
            w_lds[(kq * 4 + 2) * S_CODES + code] = v.z;
            w_lds[(kq * 4 + 3) * S_CODES + code] = v.w;
        }
        if (chunk + 1 < 32) {
            int k0n = (chunk + 1) * 8;
#pragma unroll
            for (int m = 0; m < 8; ++m) {
                int fid = m * 256 + tid;
                int code = fid >> 1, kq = fid & 1;
                pre[m] = *(const float4*)(emb + (size_t)code * C_DIM + k0n + kq * 4);
            }
        }
        __syncthreads();
        int k0 = chunk * 8;
#pragma unroll
        for (int kk = 0; kk < 8; ++kk) {
            int k = k0 + kk;
            float4 wq0 = *(const float4*)&w_lds[kk * S_CODES +   0 + l * 4];
            float4 wq1 = *(const float4*)&w_lds[kk * S_CODES + 256 + l * 4];
            float4 wq2 = *(const float4*)&w_lds[kk * S_CODES + 512 + l * 4];
            float4 wq3 = *(const float4*)&w_lds[kk * S_CODES + 768 + l * 4];
            float4 xa = *(const float4*)&x_lds[k * 32 + wv * 8];
            float4 xb = *(const float4*)&x_lds[k * 32 + wv * 8 + 4];
            float xs[8] = {xa.x, xa.y, xa.z, xa.w, xb.x, xb.y, xb.z, xb.w};
            float wvv[16] = {wq0.x, wq0.y, wq0.z, wq0.w, wq1.x, wq1.y, wq1.z, wq1.w,
                             wq2.x, wq2.y, wq2.z, wq2.w, wq3.x, wq3.y, wq3.z, wq3.w};
#pragma unroll
            for (int t = 0; t < 8; ++t) {
                float xv = xs[t];
#pragma unroll
                for (int j = 0; j < 16; ++j) acc[t][j] = fmaf(xv, wvv[j], acc[t][j]);
            }
        }
        __syncthreads();
    }
    float w2v[16];
#pragma unroll
    for (int m = 0; m < 4; ++m) {
        float4 v = *(const float4*)&w2[m * 256 + l * 4];
        w2v[m*4+0] = v.x; w2v[m*4+1] = v.y; w2v[m*4+2] = v.z; w2v[m*4+3] = v.w;
    }
    int* idx_sh = (int*)w_lds;
    float* red = (float*)(w_lds + 64);
#pragma unroll
    for (int t = 0; t < 8; ++t) {
        float bv = FLT_MAX; int bi = 0;
#pragma unroll
        for (int m = 0; m < 4; ++m)
#pragma unroll
            for (int j = 0; j < 4; ++j) {
                float s = w2v[m*4+j] - 2.f * acc[t][m*4+j];
                int c = m * 256 + l * 4 + j;
                if (s < bv) { bv = s; bi = c; }
            }
#pragma unroll
        for (int off = 32; off > 0; off >>= 1) {
            float ov = __shfl_xor(bv, off);
            int oi = __shfl_xor(bi, off);
            if (ov < bv || (ov == bv && oi < bi)) { bv = ov; bi = oi; }
        }
        if (l == 0) idx_sh[wv * 8 + t] = bi;
    }
    __syncthreads();
    if (tid < 32) atomicAdd(&hist[idx_sh[tid]], 1);
    float lsum = 0.f;
    for (int e = tid; e < C_DIM * 32; e += 256) {
        int t = e & 31, c = e >> 5;
        int id = idx_sh[t];
        float q = emb[(size_t)id * C_DIM + c];
        float xv = x_lds[c * 32 + t];
        float d = q - xv;
        lsum += d * d;
        out[((size_t)(b * C_DIM + c) << 10) + hw0 + t] = q;
    }
#pragma unroll
    for (int off = 32; off > 0; off >>= 1) lsum += __shfl_down(lsum, off);
    if (l == 0) red[wv] = lsum;
    __syncthreads();
    if (tid == 0) atomicAdd(lossp, red[0] + red[1] + red[2] + red[3]);
}

__global__ void finalize_kernel(const int* __restrict__ hist, const float* __restrict__ lossp,
                                float* __restrict__ out) {
    __shared__ float red[16];
    int tid = threadIdx.x;                  // 1024 threads
    float p = (float)hist[tid] * (1.f / 32768.f);
    float term = p * logf(p + 1e-6f);
#pragma unroll
    for (int off = 32; off > 0; off >>= 1) term += __shfl_down(term, off);
    if ((tid & 63) == 0) red[tid >> 6] = term;
    __syncthreads();
    if (tid == 0) {
        float s = 0.f;
#pragma unroll
        for (int i = 0; i < 16; ++i) s += red[i];
        out[8388608] = 0.25f * lossp[0] * (1.f / 8388608.f);
        out[8388609] = expf(-s);
    }
}

extern "C" void kernel_launch(void* const* d_in, const int* in_sizes, int n_in,
                              void* d_out, int out_size, void* d_ws, size_t ws_size,
                              hipStream_t stream) {
    const float* x   = (const float*)d_in[0];
    const float* emb = (const float*)d_in[1];
    float* out = (float*)d_out;
    char* ws = (char*)d_ws;
    int*   hist  = (int*)(ws + WS_HIST);
    float* lossp = (float*)(ws + WS_LOSS);
    float* w2    = (float*)(ws + WS_W2);

    hipMemsetAsync(d_ws, 0, 4608, stream);   // hist + loss accumulator

    if (ws_size >= WS_NEED) {
        unsigned short* xhi = (unsigned short*)(ws + WS_XHI);
        unsigned short* xlo = (unsigned short*)(ws + WS_XLO);
        unsigned short* whi = (unsigned short*)(ws + WS_WHI);
        unsigned short* wlo = (unsigned short*)(ws + WS_WLO);
        float* pval = (float*)(ws + WS_PVAL);
        int*   pidx = (int*)(ws + WS_PIDX);
        split_w<<<1024, 64, 0, stream>>>(emb, whi, wlo, w2);
        split_x<<<2048, 256, 0, stream>>>(x, xhi, xlo);
        vq_mfma<<<512, 256, 0, stream>>>(xhi, xlo, whi, wlo, w2, pval, pidx);
        emit<<<256, 256, 0, stream>>>(x, emb, pval, pidx, out, hist, lossp);
    } else {
        w2_kernel<<<4, 256, 0, stream>>>(emb, w2);
        vq_main<<<1024, 256, 0, stream>>>(x, emb, out, hist, lossp, w2);
    }
    finalize_kernel<<<1, 1024, 0, stream>>>(hist, lossp, out);
}

// Round 3
// 153.819 us; speedup vs baseline: 3.3342x; 1.1679x over previous
//
#include <hip/hip_runtime.h>
#include <hip/hip_bf16.h>
#include <cfloat>
#include <math.h>

#define N_TOK   32768
#define S_CODES 1024
#define C_DIM   256

typedef __attribute__((ext_vector_type(8))) short short8v;
typedef __attribute__((ext_vector_type(4))) float float4v;

// ---- workspace byte offsets ----
#define WS_HIST 0                       // 1024 int
#define WS_LOSS 4096                    // 1 float
#define WS_W2   4608                    // 1024 float
#define WS_WHI  16384                   // 1024*256 bf16 = 512 KB
#define WS_WLO  (WS_WHI + 524288)
#define WS_NEED ((size_t)(WS_WLO + 524288))

__device__ __forceinline__ unsigned short f2bf(float f) {
    __hip_bfloat16 h = __float2bfloat16(f);
    return __builtin_bit_cast(unsigned short, h);
}
__device__ __forceinline__ float bf2f(unsigned short u) {
    return __bfloat162float(__builtin_bit_cast(__hip_bfloat16, u));
}
__device__ __forceinline__ void gload16(const void* g, void* l) {
    __builtin_amdgcn_global_load_lds((const __attribute__((address_space(1))) void*)g,
                                     (__attribute__((address_space(3))) void*)l, 16, 0, 0);
}

// ---- split w into bf16 hi/lo + squared norms ----
__global__ void split_w(const float* __restrict__ w, unsigned short* __restrict__ whi,
                        unsigned short* __restrict__ wlo, float* __restrict__ w2) {
    int c = blockIdx.x, l = threadIdx.x;       // 1024 blocks x 64 threads
    float4 v = ((const float4*)(w + (size_t)c * C_DIM))[l];
    float s = v.x*v.x + v.y*v.y + v.z*v.z + v.w*v.w;
    float vv[4] = {v.x, v.y, v.z, v.w};
    ushort4 h, lo;
    unsigned short* hp = (unsigned short*)&h;
    unsigned short* lp = (unsigned short*)&lo;
#pragma unroll
    for (int q = 0; q < 4; ++q) {
        hp[q] = f2bf(vv[q]);
        lp[q] = f2bf(vv[q] - bf2f(hp[q]));
    }
    *(ushort4*)&whi[(size_t)c * C_DIM + l*4] = h;
    *(ushort4*)&wlo[(size_t)c * C_DIM + l*4] = lo;
#pragma unroll
    for (int off = 32; off > 0; off >>= 1) s += __shfl_down(s, off);
    if (l == 0) w2[c] = s;
}

// ---- fused: stage+convert x, split-bf16 MFMA vs all 1024 codes, argmin,
//      histogram, gather, out-write, loss (= bestscore + sum x^2) ----
// grid 512 blocks of 64 tokens; 256 threads; LDS ~52 KB -> 2 blocks/CU
__global__ void __launch_bounds__(256, 2)
vq_fused(const float* __restrict__ x, const float* __restrict__ emb,
         const unsigned short* __restrict__ whi, const unsigned short* __restrict__ wlo,
         const float* __restrict__ w2g, float* __restrict__ out,
         int* __restrict__ hist, float* __restrict__ lossp) {
    __shared__ float xf32[32 * 65];                      // padded f32 transpose tile
    __shared__ __align__(16) unsigned short xh[64 * 32]; // [t][k-chunk swizzled]
    __shared__ __align__(16) unsigned short xl[64 * 32];
    __shared__ __align__(16) unsigned short wh[256 * 32];
    __shared__ __align__(16) unsigned short wl[256 * 32];
    __shared__ float x2acc[64];
    __shared__ float bestv[4][64];
    __shared__ int   besti[4][64];
    __shared__ int   idx_sh[64];

    const int tid = threadIdx.x;
    const int l = tid & 63, wv = tid >> 6;
    const int quad = l >> 4, lr = l & 15;
    const int t0 = blockIdx.x * 64;
    const int b = t0 >> 10, hw0 = t0 & 1023;
    const size_t xbase = ((size_t)b << 18) + hw0;        // b*256*1024 + hw0

    if (tid < 64) x2acc[tid] = 0.f;

    float bval[16]; int bidx[16];
#pragma unroll
    for (int s2 = 0; s2 < 16; ++s2) { bval[s2] = FLT_MAX; bidx[s2] = 0; }

    // DMA lane roles (16 rows x 4 chunks of 16B per instr, XOR swizzle)
    const int srow = l >> 2;
    const int sch  = (l & 3) ^ (srow & 3);
    const char* whic = (const char*)whi;
    const char* wloc = (const char*)wlo;
    char* whlds = (char*)wh;
    char* wllds = (char*)wl;

    // conversion roles: token ct, k-subchunk ckq (8 k each)
    const int ct = tid & 63;
    const int ckq = tid >> 6;
    // x f32 staging roles
    const int sc0 = tid >> 4, su = tid & 15;             // fid = tid
    const int sc1 = 16 + sc0;                            // fid = 256+tid (same u)

    const float4v zacc = {0.f, 0.f, 0.f, 0.f};

    for (int s = 0; s < 4; ++s) {
        float4v acc[4][4];
#pragma unroll
        for (int i = 0; i < 4; ++i)
#pragma unroll
            for (int j = 0; j < 4; ++j) acc[i][j] = zacc;
        float w2v[4];
#pragma unroll
        for (int j = 0; j < 4; ++j) w2v[j] = w2g[s*256 + wv*64 + j*16 + lr];

        for (int kc = 0; kc < 8; ++kc) {
            __syncthreads();                             // prev reads of all LDS done
            // x f32 vector loads (issued before DMA so their wait leaves DMA in flight)
            float4 xv0 = *(const float4*)(x + xbase + (size_t)(kc*32 + sc0)*1024 + su*4);
            float4 xv1 = *(const float4*)(x + xbase + (size_t)(kc*32 + sc1)*1024 + su*4);
            // w hi/lo DMA into swizzled LDS
#pragma unroll
            for (int q = 0; q < 4; ++q) {
                int rb = wv*64 + q*16;
                size_t go = (size_t)(s*256 + rb + srow)*512 + (size_t)kc*64 + sch*16;
                gload16(whic + go, whlds + rb*64);
                gload16(wloc + go, wllds + rb*64);
            }
            // park x f32 in padded LDS tile
            xf32[sc0*65 + su*4 + 0] = xv0.x;
            xf32[sc0*65 + su*4 + 1] = xv0.y;
            xf32[sc0*65 + su*4 + 2] = xv0.z;
            xf32[sc0*65 + su*4 + 3] = xv0.w;
            xf32[sc1*65 + su*4 + 0] = xv1.x;
            xf32[sc1*65 + su*4 + 1] = xv1.y;
            xf32[sc1*65 + su*4 + 2] = xv1.z;
            xf32[sc1*65 + su*4 + 3] = xv1.w;
            __syncthreads();                             // xf32 ready
            // transpose-read + hi/lo convert + x^2 partial
            short8v hv, lv;
            float vsum = 0.f;
#pragma unroll
            for (int j2 = 0; j2 < 8; ++j2) {
                float v = xf32[(ckq*8 + j2)*65 + ct];
                unsigned short h = f2bf(v);
                float hf = bf2f(h);
                unsigned short lo = f2bf(v - hf);
                hv[j2] = (short)h; lv[j2] = (short)lo;
                vsum = fmaf(v, v, vsum);
            }
            int xo = ct*32 + ((ckq ^ (ct & 3)) << 3);
            *(short8v*)&xh[xo] = hv;
            *(short8v*)&xl[xo] = lv;
            if (s == 0) atomicAdd(&x2acc[ct], vsum);
            __syncthreads();                             // xh/xl + DMA visible
            // compute: 16 frag reads, 48 MFMAs
            short8v ah[4], al[4], bh4[4], bl4[4];
#pragma unroll
            for (int i = 0; i < 4; ++i) {
                int arow = i*16 + lr;
                int ao = arow*32 + ((quad ^ (arow & 3)) << 3);
                ah[i] = *(const short8v*)&xh[ao];
                al[i] = *(const short8v*)&xl[ao];
            }
#pragma unroll
            for (int j = 0; j < 4; ++j) {
                int brow = wv*64 + j*16 + lr;
                int bo = brow*32 + ((quad ^ (brow & 3)) << 3);
                bh4[j] = *(const short8v*)&wh[bo];
                bl4[j] = *(const short8v*)&wl[bo];
            }
#pragma unroll
            for (int i = 0; i < 4; ++i)
#pragma unroll
                for (int j = 0; j < 4; ++j) {
                    acc[i][j] = __builtin_amdgcn_mfma_f32_16x16x32_bf16(ah[i], bh4[j], acc[i][j], 0, 0, 0);
                    acc[i][j] = __builtin_amdgcn_mfma_f32_16x16x32_bf16(ah[i], bl4[j], acc[i][j], 0, 0, 0);
                    acc[i][j] = __builtin_amdgcn_mfma_f32_16x16x32_bf16(al[i], bh4[j], acc[i][j], 0, 0, 0);
                }
        }
        // fold strip scores into running per-token argmin
#pragma unroll
        for (int j = 0; j < 4; ++j) {
            int code = s*256 + wv*64 + j*16 + lr;
#pragma unroll
            for (int i = 0; i < 4; ++i)
#pragma unroll
                for (int rr = 0; rr < 4; ++rr) {
                    float sv = fmaf(-2.f, acc[i][j][rr], w2v[j]);
                    int slot = i*4 + rr;
                    if (sv < bval[slot]) { bval[slot] = sv; bidx[slot] = code; }
                }
        }
    }

    // reduce over the 16 lr-lanes (code dim) within each quad
#pragma unroll
    for (int slot = 0; slot < 16; ++slot) {
        float bv = bval[slot]; int bi = bidx[slot];
#pragma unroll
        for (int off = 1; off < 16; off <<= 1) {
            float ov = __shfl_xor(bv, off);
            int   oi = __shfl_xor(bi, off);
            if (ov < bv || (ov == bv && oi < bi)) { bv = ov; bi = oi; }
        }
        if (lr == 0) {
            int tok = (slot >> 2)*16 + quad*4 + (slot & 3);
            bestv[wv][tok] = bv; besti[wv][tok] = bi;
        }
    }
    __syncthreads();
    if (tid < 64) {
        float bv = bestv[0][tid]; int bi = besti[0][tid];
#pragma unroll
        for (int w = 1; w < 4; ++w) {
            float ov = bestv[w][tid]; int oi = besti[w][tid];
            if (ov < bv || (ov == bv && oi < bi)) { bv = ov; bi = oi; }
        }
        idx_sh[tid] = bi;
        atomicAdd(&hist[bi], 1);
        // |q - x|^2 = (w2 - 2 q.x) + x^2  -> commitment-loss partial
        float lsum = bv + x2acc[tid];
#pragma unroll
        for (int off = 32; off > 0; off >>= 1) lsum += __shfl_down(lsum, off);
        if (tid == 0) atomicAdd(lossp, lsum);
    }
    __syncthreads();
    // gather + coalesced out write
    {
        int t = tid & 63, cq = tid >> 6;
        int id = idx_sh[t];
        const float* erow = emb + (size_t)id * C_DIM;
        float* ob = out + xbase + t;
#pragma unroll
        for (int cb = 0; cb < 16; ++cb) {
            int c4 = cb*16 + cq*4;
            float4 q4 = *(const float4*)&erow[c4];
            ob[(size_t)(c4+0)*1024] = q4.x;
            ob[(size_t)(c4+1)*1024] = q4.y;
            ob[(size_t)(c4+2)*1024] = q4.z;
            ob[(size_t)(c4+3)*1024] = q4.w;
        }
    }
}

__global__ void finalize_kernel(const int* __restrict__ hist, const float* __restrict__ lossp,
                                float* __restrict__ out) {
    __shared__ float red[16];
    int tid = threadIdx.x;                  // 1024 threads
    float p = (float)hist[tid] * (1.f / 32768.f);
    float term = p * logf(p + 1e-6f);
#pragma unroll
    for (int off = 32; off > 0; off >>= 1) term += __shfl_down(term, off);
    if ((tid & 63) == 0) red[tid >> 6] = term;
    __syncthreads();
    if (tid == 0) {
        float s = 0.f;
#pragma unroll
        for (int i = 0; i < 16; ++i) s += red[i];
        out[8388608] = 0.25f * lossp[0] * (1.f / 8388608.f);   // quant_loss
        out[8388609] = expf(-s);                               // perplexity
    }
}

// ---- fallback path (round-1 kernel, known-correct) used only if ws too small ----
__global__ void w2_kernel(const float* __restrict__ w, float* __restrict__ w2) {
    int code = blockIdx.x * blockDim.x + threadIdx.x;
    const float4* r = (const float4*)(w + (size_t)code * C_DIM);
    float s = 0.f;
#pragma unroll 8
    for (int i = 0; i < C_DIM / 4; ++i) {
        float4 v = r[i];
        s += v.x * v.x + v.y * v.y + v.z * v.z + v.w * v.w;
    }
    w2[code] = s;
}

__launch_bounds__(256, 2)
__global__ void vq_main(const float* __restrict__ x, const float* __restrict__ emb,
                        float* __restrict__ out, int* __restrict__ hist,
                        float* __restrict__ lossp, const float* __restrict__ w2) {
    __shared__ float w_lds[8 * S_CODES];
    __shared__ float x_lds[C_DIM * 32];
    const int tid = threadIdx.x;
    const int l = tid & 63, wv = tid >> 6;
    const int t0 = blockIdx.x * 32;
    const int b = t0 >> 10, hw0 = t0 & 1023;
    const float* xbase = x + ((size_t)b * C_DIM << 10) + hw0;
    {
        int rl = tid & 7, r0 = tid >> 3;
        for (int rep = 0; rep < 8; ++rep) {
            int c = rep * 32 + r0;
            float4 v = *(const float4*)(xbase + ((size_t)c << 10) + rl * 4);
            *(float4*)&x_lds[c * 32 + rl * 4] = v;
        }
    }
    float4 pre[8];
#pragma unroll
    for (int m = 0; m < 8; ++m) {
        int fid = m * 256 + tid;
        int code = fid >> 1, kq = fid & 1;
        pre[m] = *(const float4*)(emb + (size_t)code * C_DIM + kq * 4);
    }
    float acc[8][16];
#pragma unroll
    for (int t = 0; t < 8; ++t)
#pragma unroll
        for (int j = 0; j < 16; ++j) acc[t][j] = 0.f;
    __syncthreads();
    for (int chunk = 0; chunk < 32; ++chunk) {
#pragma unroll
        for (int m = 0; m < 8; ++m) {
            int fid = m * 256 + tid;
            int code = fid >> 1, kq = fid & 1;
            float4 v = pre[m];
            w_lds[(kq * 4 + 0) * S_CODES + code] = v.x;
            w_lds[(kq * 4 + 1) * S_CODES + code] = v.y;
            w_lds[(kq * 4 + 2) * S_CODES + code] = v.z;
            w_lds[(kq * 4 + 3) * S_CODES + code] = v.w;
        }
        if (chunk + 1 < 32) {
            int k0n = (chunk + 1) * 8;
#pragma unroll
            for (int m = 0; m < 8; ++m) {
                int fid = m * 256 + tid;
                int code = fid >> 1, kq = fid & 1;
                pre[m] = *(const float4*)(emb + (size_t)code * C_DIM + k0n + kq * 4);
            }
        }
        __syncthreads();
        int k0 = chunk * 8;
#pragma unroll
        for (int kk = 0; kk < 8; ++kk) {
            int k = k0 + kk;
            float4 wq0 = *(const float4*)&w_lds[kk * S_CODES +   0 + l * 4];
            float4 wq1 = *(const float4*)&w_lds[kk * S_CODES + 256 + l * 4];
            float4 wq2 = *(const float4*)&w_lds[kk * S_CODES + 512 + l * 4];
            float4 wq3 = *(const float4*)&w_lds[kk * S_CODES + 768 + l * 4];
            float4 xa = *(const float4*)&x_lds[k * 32 + wv * 8];
            float4 xb = *(const float4*)&x_lds[k * 32 + wv * 8 + 4];
            float xs[8] = {xa.x, xa.y, xa.z, xa.w, xb.x, xb.y, xb.z, xb.w};
            float wvv[16] = {wq0.x, wq0.y, wq0.z, wq0.w, wq1.x, wq1.y, wq1.z, wq1.w,
                             wq2.x, wq2.y, wq2.z, wq2.w, wq3.x, wq3.y, wq3.z, wq3.w};
#pragma unroll
            for (int t = 0; t < 8; ++t) {
                float xv = xs[t];
#pragma unroll
                for (int j = 0; j < 16; ++j) acc[t][j] = fmaf(xv, wvv[j], acc[t][j]);
            }
        }
        __syncthreads();
    }
    float w2v[16];
#pragma unroll
    for (int m = 0; m < 4; ++m) {
        float4 v = *(const float4*)&w2[m * 256 + l * 4];
        w2v[m*4+0] = v.x; w2v[m*4+1] = v.y; w2v[m*4+2] = v.z; w2v[m*4+3] = v.w;
    }
    int* idx_sh = (int*)w_lds;
    float* red = (float*)(w_lds + 64);
#pragma unroll
    for (int t = 0; t < 8; ++t) {
        float bv = FLT_MAX; int bi = 0;
#pragma unroll
        for (int m = 0; m < 4; ++m)
#pragma unroll
            for (int j = 0; j < 4; ++j) {
                float s = w2v[m*4+j] - 2.f * acc[t][m*4+j];
                int c = m * 256 + l * 4 + j;
                if (s < bv) { bv = s; bi = c; }
            }
#pragma unroll
        for (int off = 32; off > 0; off >>= 1) {
            float ov = __shfl_xor(bv, off);
            int oi = __shfl_xor(bi, off);
            if (ov < bv || (ov == bv && oi < bi)) { bv = ov; bi = oi; }
        }
        if (l == 0) idx_sh[wv * 8 + t] = bi;
    }
    __syncthreads();
    if (tid < 32) atomicAdd(&hist[idx_sh[tid]], 1);
    float lsum = 0.f;
    for (int e = tid; e < C_DIM * 32; e += 256) {
        int t = e & 31, c = e >> 5;
        int id = idx_sh[t];
        float q = emb[(size_t)id * C_DIM + c];
        float xv = x_lds[c * 32 + t];
        float d = q - xv;
        lsum += d * d;
        out[((size_t)(b * C_DIM + c) << 10) + hw0 + t] = q;
    }
#pragma unroll
    for (int off = 32; off > 0; off >>= 1) lsum += __shfl_down(lsum, off);
    if (l == 0) red[wv] = lsum;
    __syncthreads();
    if (tid == 0) atomicAdd(lossp, red[0] + red[1] + red[2] + red[3]);
}

extern "C" void kernel_launch(void* const* d_in, const int* in_sizes, int n_in,
                              void* d_out, int out_size, void* d_ws, size_t ws_size,
                              hipStream_t stream) {
    const float* x   = (const float*)d_in[0];
    const float* emb = (const float*)d_in[1];
    float* out = (float*)d_out;
    char* ws = (char*)d_ws;
    int*   hist  = (int*)(ws + WS_HIST);
    float* lossp = (float*)(ws + WS_LOSS);
    float* w2    = (float*)(ws + WS_W2);

    hipMemsetAsync(d_ws, 0, 4608, stream);   // hist + loss accumulator

    if (ws_size >= WS_NEED) {
        unsigned short* whi = (unsigned short*)(ws + WS_WHI);
        unsigned short* wlo = (unsigned short*)(ws + WS_WLO);
        split_w<<<1024, 64, 0, stream>>>(emb, whi, wlo, w2);
        vq_fused<<<512, 256, 0, stream>>>(x, emb, whi, wlo, w2, out, hist, lossp);
    } else {
        w2_kernel<<<4, 256, 0, stream>>>(emb, w2);
        vq_main<<<1024, 256, 0, stream>>>(x, emb, out, hist, lossp, w2);
    }
    finalize_kernel<<<1, 1024, 0, stream>>>(hist, lossp, out);
}

// Round 4
// 146.913 us; speedup vs baseline: 3.4909x; 1.0470x over previous
//
#include <hip/hip_runtime.h>
#include <hip/hip_bf16.h>
#include <cfloat>
#include <math.h>

#define N_TOK   32768
#define S_CODES 1024
#define C_DIM   256

typedef __attribute__((ext_vector_type(8))) short short8v;
typedef __attribute__((ext_vector_type(4))) float float4v;

// ---- workspace byte offsets ----
#define WS_HIST 0                       // 1024 int
#define WS_LOSS 4096                    // 1 float
#define WS_W2   4608                    // 1024 float
#define WS_WPK  16384                   // w_packed [1024 codes][8 kc][hi 64B | lo 64B] = 1 MB
#define WS_NEED ((size_t)(WS_WPK + 1048576))

__device__ __forceinline__ unsigned short f2bf(float f) {
    __hip_bfloat16 h = __float2bfloat16(f);
    return __builtin_bit_cast(unsigned short, h);
}
__device__ __forceinline__ float bf2f(unsigned short u) {
    return __bfloat162float(__builtin_bit_cast(__hip_bfloat16, u));
}
__device__ __forceinline__ void gload16(const void* g, void* l) {
    __builtin_amdgcn_global_load_lds((const __attribute__((address_space(1))) void*)g,
                                     (__attribute__((address_space(3))) void*)l, 16, 0, 0);
}

// ---- split w into packed hi/lo rows + squared norms; also zero hist/loss ----
__global__ void split_w(const float* __restrict__ w, unsigned short* __restrict__ wpack,
                        float* __restrict__ w2, int* __restrict__ hist,
                        float* __restrict__ lossp) {
    int c = blockIdx.x, l = threadIdx.x;       // 1024 blocks x 64 threads
    float4 v = ((const float4*)(w + (size_t)c * C_DIM))[l];   // k = l*4 .. +3
    float s = v.x*v.x + v.y*v.y + v.z*v.z + v.w*v.w;
    float vv[4] = {v.x, v.y, v.z, v.w};
    ushort4 h4, l4;
    unsigned short* hp = (unsigned short*)&h4;
    unsigned short* lp = (unsigned short*)&l4;
#pragma unroll
    for (int q = 0; q < 4; ++q) {
        hp[q] = f2bf(vv[q]);
        lp[q] = f2bf(vv[q] - bf2f(hp[q]));
    }
    // kc = l>>3 (32-k chunk), offset within chunk = (l&7)*4 shorts
    size_t base = ((size_t)c * 8 + (l >> 3)) * 64;            // 64 shorts = 128 B per (c,kc)
    *(ushort4*)&wpack[base + (l & 7) * 4] = h4;               // hi half (bytes 0..63)
    *(ushort4*)&wpack[base + 32 + (l & 7) * 4] = l4;          // lo half (bytes 64..127)
#pragma unroll
    for (int off = 32; off > 0; off >>= 1) s += __shfl_down(s, off);
    if (l == 0) w2[c] = s;
    if (l == 32) hist[c] = 0;
    if (c == 0 && l == 33) *lossp = 0.f;
}

// ---- main: convert x once to full-K LDS hi/lo, stream packed w, MFMA, argmin,
//      histogram, gather, out-write, loss = best_score + sum(x^2) ----
// grid 512 blocks of 64 tokens x all 1024 codes; 256 thr; LDS 80 KB -> 2 blocks/CU
__global__ void __launch_bounds__(256, 2)
vq_fused(const float* __restrict__ x, const float* __restrict__ emb,
         const unsigned short* __restrict__ wpack, const float* __restrict__ w2g,
         float* __restrict__ out, int* __restrict__ hist, float* __restrict__ lossp) {
    __shared__ __align__(16) char smem[81920];
    // layout: xh [64 tok][256 k] bf16 (32 KB) | xl (32 KB) | w tile 16 KB (multi-use)
    unsigned short* xh = (unsigned short*)smem;
    unsigned short* xl = (unsigned short*)(smem + 32768);
    char* wt = smem + 65536;

    const int tid = threadIdx.x;
    const int l = tid & 63, wv = tid >> 6;
    const int quad = l >> 4, lr = l & 15;
    const int t0 = blockIdx.x * 64;
    const int b = t0 >> 10, hw0 = t0 & 1023;
    const size_t xbase = ((size_t)b << 18) + hw0;

    // ---- phase 1: stage + convert x (once) ----
    float x2tok = 0.f;                        // valid in wave 0 lanes (token = tid)
    {
        float* xf32 = (float*)wt;             // [32 k][68] padded overlay in w region
        const int srow = tid >> 3, scol = (tid & 7) * 8;
        const int ct = tid & 63, ckq = tid >> 6;
        float x2p = 0.f;
        for (int kc = 0; kc < 8; ++kc) {
            __syncthreads();                  // xf32 free
            const float* gp = x + xbase + (size_t)(kc * 32 + srow) * 1024 + scol;
            float4 a0 = *(const float4*)gp;
            float4 a1 = *(const float4*)(gp + 4);
            *(float4*)&xf32[srow * 68 + scol] = a0;
            *(float4*)&xf32[srow * 68 + scol + 4] = a1;
            __syncthreads();                  // xf32 ready
            short8v hv, lv;
#pragma unroll
            for (int j2 = 0; j2 < 8; ++j2) {
                float v = xf32[(ckq * 8 + j2) * 68 + ct];
                unsigned short h = f2bf(v);
                float hf = bf2f(h);
                unsigned short lo = f2bf(v - hf);
                hv[j2] = (short)h; lv[j2] = (short)lo;
                x2p = fmaf(v, v, x2p);
            }
            int pos = (kc * 4 + ckq) ^ (ct & 31);           // XOR swizzle, 16B chunks
            *(short8v*)&xh[ct * 256 + pos * 8] = hv;
            *(short8v*)&xl[ct * 256 + pos * 8] = lv;
        }
        __syncthreads();
        float* x2sh = (float*)(wt + 8704);
        x2sh[ckq * 64 + ct] = x2p;
        __syncthreads();
        if (tid < 64)
            x2tok = x2sh[tid] + x2sh[64 + tid] + x2sh[128 + tid] + x2sh[192 + tid];
    }

    // ---- precomputed fragment offsets ----
    int aoffb[4], axor[4];
#pragma unroll
    for (int i = 0; i < 4; ++i) {
        int arow = i * 16 + lr;
        aoffb[i] = arow * 512;                // bytes (row = 256 shorts)
        axor[i] = arow & 31;
    }
    int boff_h[2], boff_l[2];
#pragma unroll
    for (int j = 0; j < 2; ++j) {
        int brow = wv * 32 + j * 16 + lr;     // row in 128-code tile, 128 B rows
        boff_h[j] = brow * 128 + ((quad ^ (brow & 7)) * 16);
        boff_l[j] = brow * 128 + (((4 + quad) ^ (brow & 7)) * 16);
    }
    const int drq = l >> 3;                   // DMA: row within 8-row group
    const int dch = (l & 7) ^ (drq & 7);      // source chunk (un-swizzle)
    const char* wpc = (const char*)wpack;

    float bval[16]; int bidx[16];
#pragma unroll
    for (int s2 = 0; s2 < 16; ++s2) { bval[s2] = FLT_MAX; bidx[s2] = 0; }
    const float4v zacc = {0.f, 0.f, 0.f, 0.f};

    // ---- phase 2: 8 strips x 8 kc, 2-barrier K-loop ----
    for (int s = 0; s < 8; ++s) {
        float4v acc[4][2];
#pragma unroll
        for (int i = 0; i < 4; ++i)
#pragma unroll
            for (int j = 0; j < 2; ++j) acc[i][j] = zacc;

        for (int kc = 0; kc < 8; ++kc) {
            __syncthreads();                  // w tile free
#pragma unroll
            for (int q = 0; q < 4; ++q) {
                int lrow = wv * 32 + q * 8;                        // uniform per wave
                int code = s * 128 + lrow + drq;
                size_t src = ((size_t)code * 8 + kc) * 128 + (size_t)dch * 16;
                gload16(wpc + src, wt + lrow * 128);
            }
            __syncthreads();                  // DMA visible

            short8v ah[4], al[4], bh[2], bl[2];
#pragma unroll
            for (int i = 0; i < 4; ++i) {
                int pos = ((kc * 4 + quad) ^ axor[i]) * 16;
                ah[i] = *(const short8v*)(smem + aoffb[i] + pos);
                al[i] = *(const short8v*)(smem + 32768 + aoffb[i] + pos);
            }
#pragma unroll
            for (int j = 0; j < 2; ++j) {
                bh[j] = *(const short8v*)(wt + boff_h[j]);
                bl[j] = *(const short8v*)(wt + boff_l[j]);
            }
#pragma unroll
            for (int i = 0; i < 4; ++i)
#pragma unroll
                for (int j = 0; j < 2; ++j) {
                    acc[i][j] = __builtin_amdgcn_mfma_f32_16x16x32_bf16(ah[i], bh[j], acc[i][j], 0, 0, 0);
                    acc[i][j] = __builtin_amdgcn_mfma_f32_16x16x32_bf16(ah[i], bl[j], acc[i][j], 0, 0, 0);
                    acc[i][j] = __builtin_amdgcn_mfma_f32_16x16x32_bf16(al[i], bh[j], acc[i][j], 0, 0, 0);
                }
        }
        // fold strip into running per-token argmin
#pragma unroll
        for (int j = 0; j < 2; ++j) {
            int code = s * 128 + wv * 32 + j * 16 + lr;
            float w2c = w2g[code];
#pragma unroll
            for (int i = 0; i < 4; ++i)
#pragma unroll
                for (int rr = 0; rr < 4; ++rr) {
                    float sv = fmaf(-2.f, acc[i][j][rr], w2c);
                    int slot = i * 4 + rr;
                    if (sv < bval[slot]) { bval[slot] = sv; bidx[slot] = code; }
                }
        }
    }

    // ---- phase 3: argmin reduce, histogram, loss, gather/write ----
    __syncthreads();                          // w tile reads done; reuse as scratch
    float* bestv = (float*)wt;                // [4][64]
    int*   besti = (int*)(wt + 1024);
    int*   idx_sh = (int*)(wt + 2048);
#pragma unroll
    for (int slot = 0; slot < 16; ++slot) {
        float bv = bval[slot]; int bi = bidx[slot];
#pragma unroll
        for (int off = 1; off < 16; off <<= 1) {
            float ov = __shfl_xor(bv, off);
            int   oi = __shfl_xor(bi, off);
            if (ov < bv || (ov == bv && oi < bi)) { bv = ov; bi = oi; }
        }
        if (lr == 0) {
            int tok = (slot >> 2) * 16 + quad * 4 + (slot & 3);
            bestv[wv * 64 + tok] = bv; besti[wv * 64 + tok] = bi;
        }
    }
    __syncthreads();
    if (tid < 64) {
        float bv = bestv[tid]; int bi = besti[tid];
#pragma unroll
        for (int w = 1; w < 4; ++w) {
            float ov = bestv[w * 64 + tid]; int oi = besti[w * 64 + tid];
            if (ov < bv || (ov == bv && oi < bi)) { bv = ov; bi = oi; }
        }
        idx_sh[tid] = bi;
        atomicAdd(&hist[bi], 1);
        float lsum = bv + x2tok;              // |q-x|^2 = (w2 - 2 q.x) + x^2
#pragma unroll
        for (int off = 32; off > 0; off >>= 1) lsum += __shfl_down(lsum, off);
        if (tid == 0) atomicAdd(lossp, lsum);
    }
    __syncthreads();
    {
        int t = tid & 63, cq = tid >> 6;
        int id = idx_sh[t];
        const float* erow = emb + (size_t)id * C_DIM;
        float* ob = out + xbase + t;
#pragma unroll
        for (int cb = 0; cb < 16; ++cb) {
            int c4 = cb * 16 + cq * 4;
            float4 q4 = *(const float4*)&erow[c4];
            ob[(size_t)(c4 + 0) * 1024] = q4.x;
            ob[(size_t)(c4 + 1) * 1024] = q4.y;
            ob[(size_t)(c4 + 2) * 1024] = q4.z;
            ob[(size_t)(c4 + 3) * 1024] = q4.w;
        }
    }
}

__global__ void finalize_kernel(const int* __restrict__ hist, const float* __restrict__ lossp,
                                float* __restrict__ out) {
    __shared__ float red[16];
    int tid = threadIdx.x;                  // 1024 threads
    float p = (float)hist[tid] * (1.f / 32768.f);
    float term = p * logf(p + 1e-6f);
#pragma unroll
    for (int off = 32; off > 0; off >>= 1) term += __shfl_down(term, off);
    if ((tid & 63) == 0) red[tid >> 6] = term;
    __syncthreads();
    if (tid == 0) {
        float s = 0.f;
#pragma unroll
        for (int i = 0; i < 16; ++i) s += red[i];
        out[8388608] = 0.25f * lossp[0] * (1.f / 8388608.f);   // quant_loss
        out[8388609] = expf(-s);                               // perplexity
    }
}

// ---- fallback path (round-1 kernel, known-correct) used only if ws too small ----
__global__ void w2_kernel(const float* __restrict__ w, float* __restrict__ w2) {
    int code = blockIdx.x * blockDim.x + threadIdx.x;
    const float4* r = (const float4*)(w + (size_t)code * C_DIM);
    float s = 0.f;
#pragma unroll 8
    for (int i = 0; i < C_DIM / 4; ++i) {
        float4 v = r[i];
        s += v.x * v.x + v.y * v.y + v.z * v.z + v.w * v.w;
    }
    w2[code] = s;
}

__launch_bounds__(256, 2)
__global__ void vq_main(const float* __restrict__ x, const float* __restrict__ emb,
                        float* __restrict__ out, int* __restrict__ hist,
                        float* __restrict__ lossp, const float* __restrict__ w2) {
    __shared__ float w_lds[8 * S_CODES];
    __shared__ float x_lds[C_DIM * 32];
    const int tid = threadIdx.x;
    const int l = tid & 63, wv = tid >> 6;
    const int t0 = blockIdx.x * 32;
    const int b = t0 >> 10, hw0 = t0 & 1023;
    const float* xbase = x + ((size_t)b * C_DIM << 10) + hw0;
    {
        int rl = tid & 7, r0 = tid >> 3;
        for (int rep = 0; rep < 8; ++rep) {
            int c = rep * 32 + r0;
            float4 v = *(const float4*)(xbase + ((size_t)c << 10) + rl * 4);
            *(float4*)&x_lds[c * 32 + rl * 4] = v;
        }
    }
    float4 pre[8];
#pragma unroll
    for (int m = 0; m < 8; ++m) {
        int fid = m * 256 + tid;
        int code = fid >> 1, kq = fid & 1;
        pre[m] = *(const float4*)(emb + (size_t)code * C_DIM + kq * 4);
    }
    float acc[8][16];
#pragma unroll
    for (int t = 0; t < 8; ++t)
#pragma unroll
        for (int j = 0; j < 16; ++j) acc[t][j] = 0.f;
    __syncthreads();
    for (int chunk = 0; chunk < 32; ++chunk) {
#pragma unroll
        for (int m = 0; m < 8; ++m) {
            int fid = m * 256 + tid;
            int code = fid >> 1, kq = fid & 1;
            float4 v = pre[m];
            w_lds[(kq * 4 + 0) * S_CODES + code] = v.x;
            w_lds[(kq * 4 + 1) * S_CODES + code] = v.y;
            w_lds[(kq * 4 + 2) * S_CODES + code] = v.z;
            w_lds[(kq * 4 + 3) * S_CODES + code] = v.w;
        }
        if (chunk + 1 < 32) {
            int k0n = (chunk + 1) * 8;
#pragma unroll
            for (int m = 0; m < 8; ++m) {
                int fid = m * 256 + tid;
                int code = fid >> 1, kq = fid & 1;
                pre[m] = *(const float4*)(emb + (size_t)code * C_DIM + k0n + kq * 4);
            }
        }
        __syncthreads();
        int k0 = chunk * 8;
#pragma unroll
        for (int kk = 0; kk < 8; ++kk) {
            int k = k0 + kk;
            float4 wq0 = *(const float4*)&w_lds[kk * S_CODES +   0 + l * 4];
            float4 wq1 = *(const float4*)&w_lds[kk * S_CODES + 256 + l * 4];
            float4 wq2 = *(const float4*)&w_lds[kk * S_CODES + 512 + l * 4];
            float4 wq3 = *(const float4*)&w_lds[kk * S_CODES + 768 + l * 4];
            float4 xa = *(const float4*)&x_lds[k * 32 + wv * 8];
            float4 xb = *(const float4*)&x_lds[k * 32 + wv * 8 + 4];
            float xs[8] = {xa.x, xa.y, xa.z, xa.w, xb.x, xb.y, xb.z, xb.w};
            float wvv[16] = {wq0.x, wq0.y, wq0.z, wq0.w, wq1.x, wq1.y, wq1.z, wq1.w,
                             wq2.x, wq2.y, wq2.z, wq2.w, wq3.x, wq3.y, wq3.z, wq3.w};
#pragma unroll
            for (int t = 0; t < 8; ++t) {
                float xv = xs[t];
#pragma unroll
                for (int j = 0; j < 16; ++j) acc[t][j] = fmaf(xv, wvv[j], acc[t][j]);
            }
        }
        __syncthreads();
    }
    float w2v[16];
#pragma unroll
    for (int m = 0; m < 4; ++m) {
        float4 v = *(const float4*)&w2[m * 256 + l * 4];
        w2v[m*4+0] = v.x; w2v[m*4+1] = v.y; w2v[m*4+2] = v.z; w2v[m*4+3] = v.w;
    }
    int* idx_sh = (int*)w_lds;
    float* red = (float*)(w_lds + 64);
#pragma unroll
    for (int t = 0; t < 8; ++t) {
        float bv = FLT_MAX; int bi = 0;
#pragma unroll
        for (int m = 0; m < 4; ++m)
#pragma unroll
            for (int j = 0; j < 4; ++j) {
                float s = w2v[m*4+j] - 2.f * acc[t][m*4+j];
                int c = m * 256 + l * 4 + j;
                if (s < bv) { bv = s; bi = c; }
            }
#pragma unroll
        for (int off = 32; off > 0; off >>= 1) {
            float ov = __shfl_xor(bv, off);
            int oi = __shfl_xor(bi, off);
            if (ov < bv || (ov == bv && oi < bi)) { bv = ov; bi = oi; }
        }
        if (l == 0) idx_sh[wv * 8 + t] = bi;
    }
    __syncthreads();
    if (tid < 32) atomicAdd(&hist[idx_sh[tid]], 1);
    float lsum = 0.f;
    for (int e = tid; e < C_DIM * 32; e += 256) {
        int t = e & 31, c = e >> 5;
        int id = idx_sh[t];
        float q = emb[(size_t)id * C_DIM + c];
        float xv = x_lds[c * 32 + t];
        float d = q - xv;
        lsum += d * d;
        out[((size_t)(b * C_DIM + c) << 10) + hw0 + t] = q;
    }
#pragma unroll
    for (int off = 32; off > 0; off >>= 1) lsum += __shfl_down(lsum, off);
    if (l == 0) red[wv] = lsum;
    __syncthreads();
    if (tid == 0) atomicAdd(lossp, red[0] + red[1] + red[2] + red[3]);
}

extern "C" void kernel_launch(void* const* d_in, const int* in_sizes, int n_in,
                              void* d_out, int out_size, void* d_ws, size_t ws_size,
                              hipStream_t stream) {
    const float* x   = (const float*)d_in[0];
    const float* emb = (const float*)d_in[1];
    float* out = (float*)d_out;
    char* ws = (char*)d_ws;
    int*   hist  = (int*)(ws + WS_HIST);
    float* lossp = (float*)(ws + WS_LOSS);
    float* w2    = (float*)(ws + WS_W2);

    if (ws_size >= WS_NEED) {
        unsigned short* wpack = (unsigned short*)(ws + WS_WPK);
        split_w<<<1024, 64, 0, stream>>>(emb, wpack, w2, hist, lossp);
        vq_fused<<<512, 256, 0, stream>>>(x, emb, wpack, w2, out, hist, lossp);
    } else {
        hipMemsetAsync(d_ws, 0, 4608, stream);
        w2_kernel<<<4, 256, 0, stream>>>(emb, w2);
        vq_main<<<1024, 256, 0, stream>>>(x, emb, out, hist, lossp, w2);
    }
    finalize_kernel<<<1, 1024, 0, stream>>>(hist, lossp, out);
}